// Round 1
// baseline (199.904 us; speedup 1.0000x reference)
//
#include <hip/hip_runtime.h>
#include <math.h>

#define F 128
#define HEADS 4
#define DHEAD 32

// ---------------------------------------------------------------------------
// K1: ft = feat @ W   (N x 128) @ (128 x 128), fp32 vector ALU.
// Block 256 threads computes a 64-row x 128-col tile; 4x8 outputs per thread.
// K staged in 32-chunks: sA 64x32 (+pad to 36 to kill row-stride conflicts),
// sB 32x128.
// ---------------------------------------------------------------------------
__global__ __launch_bounds__(256) void gemm_ft_kernel(
    const float* __restrict__ A, const float* __restrict__ W,
    float* __restrict__ ft, int N) {
  __shared__ float sA[64][36];
  __shared__ float sB[32][128];
  const int t = threadIdx.x;
  const int tx = t & 15;   // 16 col-groups of 8 cols
  const int ty = t >> 4;   // 16 row-groups of 4 rows
  const int row0 = blockIdx.x * 64;

  float acc[4][8];
#pragma unroll
  for (int r = 0; r < 4; r++)
#pragma unroll
    for (int c = 0; c < 8; c++) acc[r][c] = 0.f;

  for (int k0 = 0; k0 < F; k0 += 32) {
    __syncthreads();
    // load sA: 64 rows x 32 k = 512 float4, 2 per thread
#pragma unroll
    for (int rep = 0; rep < 2; rep++) {
      int idx = t + rep * 256;
      int r = idx >> 3, c4 = idx & 7;
      int gr = row0 + r;
      float4 v = make_float4(0.f, 0.f, 0.f, 0.f);
      if (gr < N) v = *(const float4*)&A[gr * F + k0 + c4 * 4];
      *(float4*)&sA[r][c4 * 4] = v;
    }
    // load sB: 32 k x 128 cols = 1024 float4, 4 per thread
#pragma unroll
    for (int rep = 0; rep < 4; rep++) {
      int idx = t + rep * 256;
      int r = idx >> 5, c4 = idx & 31;
      *(float4*)&sB[r][c4 * 4] = *(const float4*)&W[(k0 + r) * F + c4 * 4];
    }
    __syncthreads();
#pragma unroll
    for (int kk = 0; kk < 32; kk += 4) {
      float4 a4[4];
#pragma unroll
      for (int r = 0; r < 4; r++) a4[r] = *(const float4*)&sA[ty * 4 + r][kk];
#pragma unroll
      for (int j = 0; j < 4; j++) {
        float bv[8];
        *(float4*)&bv[0] = *(const float4*)&sB[kk + j][tx * 8];
        *(float4*)&bv[4] = *(const float4*)&sB[kk + j][tx * 8 + 4];
#pragma unroll
        for (int r = 0; r < 4; r++) {
          float av = (&a4[r].x)[j];
#pragma unroll
          for (int c = 0; c < 8; c++) acc[r][c] = fmaf(av, bv[c], acc[r][c]);
        }
      }
    }
  }
#pragma unroll
  for (int r = 0; r < 4; r++) {
    int gr = row0 + ty * 4 + r;
    if (gr < N) {
      *(float4*)&ft[gr * F + tx * 8] = *(float4*)&acc[r][0];
      *(float4*)&ft[gr * F + tx * 8 + 4] = *(float4*)&acc[r][4];
    }
  }
}

// ---------------------------------------------------------------------------
// K2: histogram of dst -> counts[N]
// ---------------------------------------------------------------------------
__global__ void hist_kernel(const int* __restrict__ dst,
                            int* __restrict__ counts, int E) {
  int i = blockIdx.x * 256 + threadIdx.x;
  if (i < E) atomicAdd(&counts[dst[i]], 1);
}

// ---------------------------------------------------------------------------
// K3: two-level exclusive scan of counts -> offs (and cursor copy)
// ---------------------------------------------------------------------------
__global__ void scan_block_kernel(const int* __restrict__ counts,
                                  int* __restrict__ offs,
                                  int* __restrict__ bsums, int N) {
  __shared__ int s[256];
  int t = threadIdx.x, i = blockIdx.x * 256 + t;
  int v = (i < N) ? counts[i] : 0;
  s[t] = v;
  __syncthreads();
  for (int d = 1; d < 256; d <<= 1) {
    int x = (t >= d) ? s[t - d] : 0;
    __syncthreads();
    s[t] += x;
    __syncthreads();
  }
  if (i < N) offs[i] = s[t] - v;  // block-local exclusive
  if (t == 255) bsums[blockIdx.x] = s[255];
}

__global__ void scan_bsums_kernel(int* __restrict__ bsums, int nb) {
  __shared__ int s[256];
  int t = threadIdx.x;
  int v = (t < nb) ? bsums[t] : 0;
  s[t] = v;
  __syncthreads();
  for (int d = 1; d < 256; d <<= 1) {
    int x = (t >= d) ? s[t - d] : 0;
    __syncthreads();
    s[t] += x;
    __syncthreads();
  }
  if (t < nb) bsums[t] = s[t] - v;  // exclusive over block sums
}

__global__ void scan_add_kernel(int* __restrict__ offs,
                                int* __restrict__ cursor,
                                const int* __restrict__ bsums, int N) {
  int i = blockIdx.x * 256 + threadIdx.x;
  if (i < N) {
    int o = offs[i] + bsums[blockIdx.x];
    offs[i] = o;
    cursor[i] = o;
  }
}

// ---------------------------------------------------------------------------
// K4: scatter src ids into CSR slots (order within a node nondeterministic;
// only perturbs fp32 summation order, far below threshold)
// ---------------------------------------------------------------------------
__global__ void scatter_kernel(const int* __restrict__ src,
                               const int* __restrict__ dst,
                               int* __restrict__ cursor,
                               int* __restrict__ csr, int E) {
  int i = blockIdx.x * 256 + threadIdx.x;
  if (i < E) {
    int d = dst[i];
    int pos = atomicAdd(&cursor[d], 1);
    csr[pos] = src[i];
  }
}

// ---------------------------------------------------------------------------
// K5: fused per-node online-softmax aggregation.
// Thread layout: 4 lanes per (node, head), 8 dims/lane.
// A node's 4 heads = 16 consecutive lanes -> each edge's ft[src] row (512 B)
// is read fully coalesced. Dot via in-thread 8-FMA + 2x shfl_xor(width=4).
// Online softmax in log2 domain (v_exp_f32 is natively 2^x).
// ---------------------------------------------------------------------------
__global__ __launch_bounds__(256) void aggregate_kernel(
    const float* __restrict__ ft, const int* __restrict__ offs,
    const int* __restrict__ counts, const int* __restrict__ csr,
    const float* __restrict__ bias, float* __restrict__ out, int N) {
  const int T = blockIdx.x * 256 + threadIdx.x;
  if (T >= N * 16) return;
  const int sub = T & 3;       // quarter of a head's D
  const int p = T >> 2;        // (node, head)
  const int h = p & 3;
  const int n = p >> 2;
  const int dimBase = h * DHEAD + sub * 8;

  float ftd[8];
  {
    float4 d0 = *(const float4*)&ft[n * F + dimBase];
    float4 d1 = *(const float4*)&ft[n * F + dimBase + 4];
    ftd[0] = d0.x; ftd[1] = d0.y; ftd[2] = d0.z; ftd[3] = d0.w;
    ftd[4] = d1.x; ftd[5] = d1.y; ftd[6] = d1.z; ftd[7] = d1.w;
  }
  const int off = offs[n];
  const int deg = counts[n];

  const float LOG2E = 1.4426950408889634f;
  float m = -INFINITY, s = 0.f;
  float acc[8];
#pragma unroll
  for (int j = 0; j < 8; j++) acc[j] = 0.f;

  for (int i = 0; i < deg; i++) {
    int sid = csr[off + i];
    float v[8];
    float4 v0 = *(const float4*)&ft[sid * F + dimBase];
    float4 v1 = *(const float4*)&ft[sid * F + dimBase + 4];
    v[0] = v0.x; v[1] = v0.y; v[2] = v0.z; v[3] = v0.w;
    v[4] = v1.x; v[5] = v1.y; v[6] = v1.z; v[7] = v1.w;

    float part = 0.f;
#pragma unroll
    for (int j = 0; j < 8; j++) part = fmaf(ftd[j], v[j], part);
    part += __shfl_xor(part, 1, 4);
    part += __shfl_xor(part, 2, 4);   // e for this (node,head), in all 4 lanes

    float el = part * LOG2E;          // log2 domain
    float mn = fmaxf(m, el);
    float scale = exp2f(m - mn);      // first edge: exp2(-inf)=0
    float w = exp2f(el - mn);
    s = fmaf(s, scale, w);
#pragma unroll
    for (int j = 0; j < 8; j++) acc[j] = fmaf(acc[j], scale, w * v[j]);
    m = mn;
  }

  float inv = (deg > 0) ? 1.f / s : 0.f;  // deg==0 -> out = bias
#pragma unroll
  for (int j = 0; j < 8; j++)
    out[n * F + dimBase + j] = acc[j] * inv + bias[dimBase + j];
}

// ---------------------------------------------------------------------------
extern "C" void kernel_launch(void* const* d_in, const int* in_sizes, int n_in,
                              void* d_out, int out_size, void* d_ws,
                              size_t ws_size, hipStream_t stream) {
  const float* feat = (const float*)d_in[0];
  const int* src = (const int*)d_in[1];
  const int* dst = (const int*)d_in[2];
  const float* W = (const float*)d_in[3];
  const float* bias = (const float*)d_in[4];
  float* out = (float*)d_out;

  const int N = in_sizes[0] / F;
  const int E = in_sizes[1];

  // workspace layout
  char* ws = (char*)d_ws;
  float* ft = (float*)ws;                       // N*128 floats = 25.6 MB
  size_t ftB = (size_t)N * F * sizeof(float);
  int* counts = (int*)(ws + ftB);               // N
  int* offs = counts + N;                       // N
  int* cursor = offs + N;                       // N
  int* bsums = cursor + N;                      // 256
  int* csr = bsums + 256;                       // E

  hipMemsetAsync(counts, 0, (size_t)N * sizeof(int), stream);

  gemm_ft_kernel<<<(N + 63) / 64, 256, 0, stream>>>(feat, W, ft, N);
  hist_kernel<<<(E + 255) / 256, 256, 0, stream>>>(dst, counts, E);

  int nb = (N + 255) / 256;  // 196 for N=50000 (must be <= 256)
  scan_block_kernel<<<nb, 256, 0, stream>>>(counts, offs, bsums, N);
  scan_bsums_kernel<<<1, 256, 0, stream>>>(bsums, nb);
  scan_add_kernel<<<nb, 256, 0, stream>>>(offs, cursor, bsums, N);

  scatter_kernel<<<(E + 255) / 256, 256, 0, stream>>>(src, dst, cursor, csr, E);

  aggregate_kernel<<<(N * 16 + 255) / 256, 256, 0, stream>>>(
      ft, offs, counts, csr, bias, out, N);
}

// Round 2
// 161.450 us; speedup vs baseline: 1.2382x; 1.2382x over previous
//
#include <hip/hip_runtime.h>
#include <math.h>

#define F 128
#define HEADS 4
#define DHEAD 32

typedef unsigned short ushort_t;

// round-to-nearest-even fp32 -> bf16
__device__ __forceinline__ ushort_t f2bf(float x) {
  unsigned u = __float_as_uint(x);
  unsigned r = u + 0x7FFFu + ((u >> 16) & 1u);
  return (ushort_t)(r >> 16);
}

// unpack 8 packed bf16 (as int4) -> 8 fp32
__device__ __forceinline__ void unpack8(const int4& r, float* v) {
  int rr[4] = {r.x, r.y, r.z, r.w};
#pragma unroll
  for (int q = 0; q < 4; q++) {
    unsigned u = (unsigned)rr[q];
    v[2 * q] = __uint_as_float(u << 16);
    v[2 * q + 1] = __uint_as_float(u & 0xFFFF0000u);
  }
}

// ---------------------------------------------------------------------------
// K1: ft = feat @ W   (N x 128) @ (128 x 128), fp32 vector ALU, bf16 output.
// ---------------------------------------------------------------------------
__global__ __launch_bounds__(256) void gemm_ft_kernel(
    const float* __restrict__ A, const float* __restrict__ W,
    ushort_t* __restrict__ ftb, int N) {
  __shared__ float sA[64][36];
  __shared__ float sB[32][128];
  const int t = threadIdx.x;
  const int tx = t & 15;   // 16 col-groups of 8 cols
  const int ty = t >> 4;   // 16 row-groups of 4 rows
  const int row0 = blockIdx.x * 64;

  float acc[4][8];
#pragma unroll
  for (int r = 0; r < 4; r++)
#pragma unroll
    for (int c = 0; c < 8; c++) acc[r][c] = 0.f;

  for (int k0 = 0; k0 < F; k0 += 32) {
    __syncthreads();
#pragma unroll
    for (int rep = 0; rep < 2; rep++) {
      int idx = t + rep * 256;
      int r = idx >> 3, c4 = idx & 7;
      int gr = row0 + r;
      float4 v = make_float4(0.f, 0.f, 0.f, 0.f);
      if (gr < N) v = *(const float4*)&A[gr * F + k0 + c4 * 4];
      *(float4*)&sA[r][c4 * 4] = v;
    }
#pragma unroll
    for (int rep = 0; rep < 4; rep++) {
      int idx = t + rep * 256;
      int r = idx >> 5, c4 = idx & 31;
      *(float4*)&sB[r][c4 * 4] = *(const float4*)&W[(k0 + r) * F + c4 * 4];
    }
    __syncthreads();
#pragma unroll
    for (int kk = 0; kk < 32; kk += 4) {
      float4 a4[4];
#pragma unroll
      for (int r = 0; r < 4; r++) a4[r] = *(const float4*)&sA[ty * 4 + r][kk];
#pragma unroll
      for (int j = 0; j < 4; j++) {
        float bv[8];
        *(float4*)&bv[0] = *(const float4*)&sB[kk + j][tx * 8];
        *(float4*)&bv[4] = *(const float4*)&sB[kk + j][tx * 8 + 4];
#pragma unroll
        for (int r = 0; r < 4; r++) {
          float av = (&a4[r].x)[j];
#pragma unroll
          for (int c = 0; c < 8; c++) acc[r][c] = fmaf(av, bv[c], acc[r][c]);
        }
      }
    }
  }
#pragma unroll
  for (int r = 0; r < 4; r++) {
    int gr = row0 + ty * 4 + r;
    if (gr < N) {
      union { ushort_t us[8]; int4 v; } pk;
#pragma unroll
      for (int c = 0; c < 8; c++) pk.us[c] = f2bf(acc[r][c]);
      *(int4*)&ftb[gr * F + tx * 8] = pk.v;
    }
  }
}

// ---------------------------------------------------------------------------
// K2: histogram of dst -> counts[N]
// ---------------------------------------------------------------------------
__global__ void hist_kernel(const int* __restrict__ dst,
                            int* __restrict__ counts, int E) {
  int i = blockIdx.x * 256 + threadIdx.x;
  if (i < E) atomicAdd(&counts[dst[i]], 1);
}

// ---------------------------------------------------------------------------
// K3: scan. block-local exclusive + block sums, then per-block bsum prefix add
// ---------------------------------------------------------------------------
__global__ void scan_block_kernel(const int* __restrict__ counts,
                                  int* __restrict__ offs,
                                  int* __restrict__ bsums, int N) {
  __shared__ int s[256];
  int t = threadIdx.x, i = blockIdx.x * 256 + t;
  int v = (i < N) ? counts[i] : 0;
  s[t] = v;
  __syncthreads();
  for (int d = 1; d < 256; d <<= 1) {
    int x = (t >= d) ? s[t - d] : 0;
    __syncthreads();
    s[t] += x;
    __syncthreads();
  }
  if (i < N) offs[i] = s[t] - v;  // block-local exclusive
  if (t == 255) bsums[blockIdx.x] = s[255];
}

// each block reduces bsums[0..bid-1] itself and adds to its offs slice
__global__ void scan_finish_kernel(int* __restrict__ offs,
                                   const int* __restrict__ bsums, int N) {
  int t = threadIdx.x, b = blockIdx.x;
  int v = (t < b) ? bsums[t] : 0;  // nb <= 256 guaranteed
#pragma unroll
  for (int d = 32; d > 0; d >>= 1) v += __shfl_down(v, d, 64);
  __shared__ int wsum[4];
  if ((t & 63) == 0) wsum[t >> 6] = v;
  __syncthreads();
  int total = wsum[0] + wsum[1] + wsum[2] + wsum[3];
  int i = b * 256 + t;
  if (i < N) offs[i] += total;
}

// ---------------------------------------------------------------------------
// K4: scatter src ids into CSR slots, advancing offs in place.
// After this kernel offs[n] == end of node n's range; start = end - counts[n].
// ---------------------------------------------------------------------------
__global__ void scatter_kernel(const int* __restrict__ src,
                               const int* __restrict__ dst,
                               int* __restrict__ offs,
                               int* __restrict__ csr, int E) {
  int i = blockIdx.x * 256 + threadIdx.x;
  if (i < E) {
    int d = dst[i];
    int pos = atomicAdd(&offs[d], 1);
    csr[pos] = src[i];
  }
}

// ---------------------------------------------------------------------------
// K5: fused per-node online-softmax aggregation, bf16 ft, 2-deep pipelined.
// 4 lanes per (node, head), 8 dims/lane; a node's 16 lanes read each edge's
// 256 B bf16 row fully coalesced.
// ---------------------------------------------------------------------------
__global__ __launch_bounds__(256) void aggregate_kernel(
    const ushort_t* __restrict__ ftb, const int* __restrict__ offs_end,
    const int* __restrict__ counts, const int* __restrict__ csr,
    const float* __restrict__ bias, float* __restrict__ out, int N) {
  const int T = blockIdx.x * 256 + threadIdx.x;
  if (T >= N * 16) return;
  const int sub = T & 3;  // quarter of a head's D
  const int p = T >> 2;   // (node, head)
  const int h = p & 3;
  const int n = p >> 2;
  const int dimBase = h * DHEAD + sub * 8;

  const int deg = counts[n];
  const int off = offs_end[n] - deg;

  float ftd[8];
  {
    int4 r = *(const int4*)&ftb[n * F + dimBase];
    unpack8(r, ftd);
  }

  const float LOG2E = 1.4426950408889634f;
  float m = -INFINITY, s = 0.f;
  float acc[8];
#pragma unroll
  for (int j = 0; j < 8; j++) acc[j] = 0.f;

#define PROCESS(RX)                                              \
  do {                                                           \
    float v[8];                                                  \
    unpack8(RX, v);                                              \
    float part = 0.f;                                            \
    _Pragma("unroll") for (int j = 0; j < 8; j++) part =         \
        fmaf(ftd[j], v[j], part);                                \
    part += __shfl_xor(part, 1, 4);                              \
    part += __shfl_xor(part, 2, 4);                              \
    float el = part * LOG2E;                                     \
    float mn = fmaxf(m, el);                                     \
    float scale = exp2f(m - mn);                                 \
    float w = exp2f(el - mn);                                    \
    s = fmaf(s, scale, w);                                       \
    _Pragma("unroll") for (int j = 0; j < 8; j++) acc[j] =       \
        fmaf(acc[j], scale, w * v[j]);                           \
    m = mn;                                                      \
  } while (0)

  int4 A = make_int4(0, 0, 0, 0), B = make_int4(0, 0, 0, 0);
  if (deg > 0) {
    int s0 = csr[off];
    A = *(const int4*)&ftb[s0 * F + dimBase];
    int s1 = csr[off + min(1, deg - 1)];
    B = *(const int4*)&ftb[s1 * F + dimBase];
  }
  int i = 0;
  for (; i + 2 <= deg; i += 2) {
    // branchless 2-ahead prefetch (clamped; duplicate loads are cache hits)
    int jA = min(i + 2, deg - 1), jB = min(i + 3, deg - 1);
    int sA2 = csr[off + jA];
    int sB2 = csr[off + jB];
    int4 nA = *(const int4*)&ftb[sA2 * F + dimBase];
    int4 nB = *(const int4*)&ftb[sB2 * F + dimBase];
    PROCESS(A);
    PROCESS(B);
    A = nA;
    B = nB;
  }
  if (i < deg) PROCESS(A);
#undef PROCESS

  float inv = (deg > 0) ? 1.f / s : 0.f;  // deg==0 -> out = bias
#pragma unroll
  for (int j = 0; j < 8; j++)
    out[n * F + dimBase + j] = acc[j] * inv + bias[dimBase + j];
}

// ---------------------------------------------------------------------------
extern "C" void kernel_launch(void* const* d_in, const int* in_sizes, int n_in,
                              void* d_out, int out_size, void* d_ws,
                              size_t ws_size, hipStream_t stream) {
  const float* feat = (const float*)d_in[0];
  const int* src = (const int*)d_in[1];
  const int* dst = (const int*)d_in[2];
  const float* W = (const float*)d_in[3];
  const float* bias = (const float*)d_in[4];
  float* out = (float*)d_out;

  const int N = in_sizes[0] / F;
  const int E = in_sizes[1];

  // workspace layout
  char* ws = (char*)d_ws;
  ushort_t* ftb = (ushort_t*)ws;                 // N*128 bf16 = 12.8 MB
  size_t ftB = (size_t)N * F * sizeof(ushort_t);
  ftB = (ftB + 255) & ~(size_t)255;
  int* counts = (int*)(ws + ftB);                // N
  int* offs = counts + N;                        // N
  int* bsums = offs + N;                         // 256
  int* csr = bsums + 256;                        // E

  hipMemsetAsync(counts, 0, (size_t)N * sizeof(int), stream);

  gemm_ft_kernel<<<(N + 63) / 64, 256, 0, stream>>>(feat, W, ftb, N);
  hist_kernel<<<(E + 255) / 256, 256, 0, stream>>>(dst, counts, E);

  int nb = (N + 255) / 256;  // 196 for N=50000 (must be <= 256)
  scan_block_kernel<<<nb, 256, 0, stream>>>(counts, offs, bsums, N);
  scan_finish_kernel<<<nb, 256, 0, stream>>>(offs, bsums, N);

  scatter_kernel<<<(E + 255) / 256, 256, 0, stream>>>(src, dst, offs, csr, E);

  aggregate_kernel<<<(N * 16 + 255) / 256, 256, 0, stream>>>(
      ftb, offs, counts, csr, bias, out, N);
}

// Round 3
// 153.124 us; speedup vs baseline: 1.3055x; 1.0544x over previous
//
#include <hip/hip_runtime.h>
#include <math.h>

#define F 128
#define HEADS 4
#define DHEAD 32

typedef unsigned short ushort_t;

// round-to-nearest-even fp32 -> bf16
__device__ __forceinline__ ushort_t f2bf(float x) {
  unsigned u = __float_as_uint(x);
  unsigned r = u + 0x7FFFu + ((u >> 16) & 1u);
  return (ushort_t)(r >> 16);
}

// unpack 8 packed bf16 (as int4) -> 8 fp32
__device__ __forceinline__ void unpack8(const int4& r, float* v) {
  int rr[4] = {r.x, r.y, r.z, r.w};
#pragma unroll
  for (int q = 0; q < 4; q++) {
    unsigned u = (unsigned)rr[q];
    v[2 * q] = __uint_as_float(u << 16);
    v[2 * q + 1] = __uint_as_float(u & 0xFFFF0000u);
  }
}

// class of a node: cls = n / 6250 via magic multiply (exact for n < 2.9e6)
#define CLS_MAGIC 687195u
__device__ __forceinline__ int node_cls(int n) {
  return (int)__umulhi((unsigned)n, CLS_MAGIC);
}

// ---------------------------------------------------------------------------
// K1: ft = feat @ W   (N x 128) @ (128 x 128), fp32 vector ALU, bf16 output.
// ---------------------------------------------------------------------------
__global__ __launch_bounds__(256) void gemm_ft_kernel(
    const float* __restrict__ A, const float* __restrict__ W,
    ushort_t* __restrict__ ftb, int N) {
  __shared__ float sA[64][36];
  __shared__ float sB[32][128];
  const int t = threadIdx.x;
  const int tx = t & 15;   // 16 col-groups of 8 cols
  const int ty = t >> 4;   // 16 row-groups of 4 rows
  const int row0 = blockIdx.x * 64;

  float acc[4][8];
#pragma unroll
  for (int r = 0; r < 4; r++)
#pragma unroll
    for (int c = 0; c < 8; c++) acc[r][c] = 0.f;

  for (int k0 = 0; k0 < F; k0 += 32) {
    __syncthreads();
#pragma unroll
    for (int rep = 0; rep < 2; rep++) {
      int idx = t + rep * 256;
      int r = idx >> 3, c4 = idx & 7;
      int gr = row0 + r;
      float4 v = make_float4(0.f, 0.f, 0.f, 0.f);
      if (gr < N) v = *(const float4*)&A[gr * F + k0 + c4 * 4];
      *(float4*)&sA[r][c4 * 4] = v;
    }
#pragma unroll
    for (int rep = 0; rep < 4; rep++) {
      int idx = t + rep * 256;
      int r = idx >> 5, c4 = idx & 31;
      *(float4*)&sB[r][c4 * 4] = *(const float4*)&W[(k0 + r) * F + c4 * 4];
    }
    __syncthreads();
#pragma unroll
    for (int kk = 0; kk < 32; kk += 4) {
      float4 a4[4];
#pragma unroll
      for (int r = 0; r < 4; r++) a4[r] = *(const float4*)&sA[ty * 4 + r][kk];
#pragma unroll
      for (int j = 0; j < 4; j++) {
        float bv[8];
        *(float4*)&bv[0] = *(const float4*)&sB[kk + j][tx * 8];
        *(float4*)&bv[4] = *(const float4*)&sB[kk + j][tx * 8 + 4];
#pragma unroll
        for (int r = 0; r < 4; r++) {
          float av = (&a4[r].x)[j];
#pragma unroll
          for (int c = 0; c < 8; c++) acc[r][c] = fmaf(av, bv[c], acc[r][c]);
        }
      }
    }
  }
#pragma unroll
  for (int r = 0; r < 4; r++) {
    int gr = row0 + ty * 4 + r;
    if (gr < N) {
      union { ushort_t us[8]; int4 v; } pk;
#pragma unroll
      for (int c = 0; c < 8; c++) pk.us[c] = f2bf(acc[r][c]);
      *(int4*)&ftb[gr * F + tx * 8] = pk.v;
    }
  }
}

// ---------------------------------------------------------------------------
// K2: histogram of dst -> counts[N]
// ---------------------------------------------------------------------------
__global__ void hist_kernel(const int* __restrict__ dst,
                            int* __restrict__ counts, int E) {
  int i = blockIdx.x * 256 + threadIdx.x;
  if (i < E) atomicAdd(&counts[dst[i]], 1);
}

// ---------------------------------------------------------------------------
// K3: scan. block-local exclusive + block sums, then per-block bsum prefix add
// ---------------------------------------------------------------------------
__global__ void scan_block_kernel(const int* __restrict__ counts,
                                  int* __restrict__ offs,
                                  int* __restrict__ bsums, int N) {
  __shared__ int s[256];
  int t = threadIdx.x, i = blockIdx.x * 256 + t;
  int v = (i < N) ? counts[i] : 0;
  s[t] = v;
  __syncthreads();
  for (int d = 1; d < 256; d <<= 1) {
    int x = (t >= d) ? s[t - d] : 0;
    __syncthreads();
    s[t] += x;
    __syncthreads();
  }
  if (i < N) offs[i] = s[t] - v;  // block-local exclusive
  if (t == 255) bsums[blockIdx.x] = s[255];
}

__global__ void scan_finish_kernel(int* __restrict__ offs,
                                   const int* __restrict__ bsums, int N) {
  int t = threadIdx.x, b = blockIdx.x;
  int v = (t < b) ? bsums[t] : 0;  // nb <= 256 guaranteed
#pragma unroll
  for (int d = 32; d > 0; d >>= 1) v += __shfl_down(v, d, 64);
  __shared__ int wsum[4];
  if ((t & 63) == 0) wsum[t >> 6] = v;
  __syncthreads();
  int total = wsum[0] + wsum[1] + wsum[2] + wsum[3];
  int i = b * 256 + t;
  if (i < N) offs[i] += total;
}

// ---------------------------------------------------------------------------
// K4: XCD-class-filtered scatter. Block class x = bid&7 commits only edges
// with dst in node-range x (6250 nodes). Every class scans all edges (dense
// coalesced reads); csr/offs lines for a range are then written by ONE XCD
// (bid%8 round-robin heuristic) -> stores merge in its L2 before writeback.
// After this kernel offs[n] == end of node n's range; start = end - counts[n].
// ---------------------------------------------------------------------------
#define SCAT_BLOCKS 2048
__global__ __launch_bounds__(256) void scatter8_kernel(
    const int* __restrict__ src, const int* __restrict__ dst,
    int* __restrict__ offs, int* __restrict__ csr, int E) {
  const int cls = blockIdx.x & 7;
  const int bx = blockIdx.x >> 3;          // class-local block index
  const int nbc = SCAT_BLOCKS / 8;         // blocks per class
  const int seg = (E + nbc - 1) / nbc;     // edges per class-block
  const int e0 = bx * seg;
  const int e1 = min(e0 + seg, E);
  for (int e = e0 + (int)threadIdx.x; e < e1; e += 256) {
    int d = dst[e];
    if (node_cls(d) == cls) {
      int pos = atomicAdd(&offs[d], 1);
      csr[pos] = src[e];
    }
  }
}

// ---------------------------------------------------------------------------
// K5: fused per-node online-softmax aggregation, bf16 ft, 4-deep pipelined.
// 4 lanes per (node, head), 8 dims/lane; a node's 16 lanes read each edge's
// 256 B bf16 row fully coalesced.
// ---------------------------------------------------------------------------
__global__ __launch_bounds__(256) void aggregate_kernel(
    const ushort_t* __restrict__ ftb, const int* __restrict__ offs_end,
    const int* __restrict__ counts, const int* __restrict__ csr,
    const float* __restrict__ bias, float* __restrict__ out, int N) {
  const int T = blockIdx.x * 256 + threadIdx.x;
  if (T >= N * 16) return;
  const int sub = T & 3;  // quarter of a head's D
  const int p = T >> 2;   // (node, head)
  const int h = p & 3;
  const int n = p >> 2;
  const int dimBase = h * DHEAD + sub * 8;

  const int deg = counts[n];
  const int off = offs_end[n] - deg;

  float ftd[8];
  {
    int4 r = *(const int4*)&ftb[n * F + dimBase];
    unpack8(r, ftd);
  }

  const float LOG2E = 1.4426950408889634f;
  float m = -INFINITY, s = 0.f;
  float acc[8];
#pragma unroll
  for (int j = 0; j < 8; j++) acc[j] = 0.f;

#define PROCESS(RX)                                              \
  do {                                                           \
    float v[8];                                                  \
    unpack8(RX, v);                                              \
    float part = 0.f;                                            \
    _Pragma("unroll") for (int j = 0; j < 8; j++) part =         \
        fmaf(ftd[j], v[j], part);                                \
    part += __shfl_xor(part, 1, 4);                              \
    part += __shfl_xor(part, 2, 4);                              \
    float el = part * LOG2E;                                     \
    float mn = fmaxf(m, el);                                     \
    float scale = exp2f(m - mn);                                 \
    float w = exp2f(el - mn);                                    \
    s = fmaf(s, scale, w);                                       \
    _Pragma("unroll") for (int j = 0; j < 8; j++) acc[j] =       \
        fmaf(acc[j], scale, w * v[j]);                           \
    m = mn;                                                      \
  } while (0)

  int4 R0 = make_int4(0, 0, 0, 0), R1 = R0, R2 = R0, R3 = R0;
  if (deg > 0) {
    int dm1 = deg - 1;
    int s0 = csr[off];
    int s1 = csr[off + min(1, dm1)];
    int s2 = csr[off + min(2, dm1)];
    int s3 = csr[off + min(3, dm1)];
    R0 = *(const int4*)&ftb[s0 * F + dimBase];
    R1 = *(const int4*)&ftb[s1 * F + dimBase];
    R2 = *(const int4*)&ftb[s2 * F + dimBase];
    R3 = *(const int4*)&ftb[s3 * F + dimBase];
  }
  int i = 0;
  for (; i + 4 <= deg; i += 4) {
    // branchless 4-ahead prefetch (clamped; duplicate loads are cache hits)
    int dm1 = deg - 1;
    int sa = csr[off + min(i + 4, dm1)];
    int sb = csr[off + min(i + 5, dm1)];
    int sc = csr[off + min(i + 6, dm1)];
    int sd = csr[off + min(i + 7, dm1)];
    int4 Na = *(const int4*)&ftb[sa * F + dimBase];
    int4 Nb = *(const int4*)&ftb[sb * F + dimBase];
    int4 Nc = *(const int4*)&ftb[sc * F + dimBase];
    int4 Nd = *(const int4*)&ftb[sd * F + dimBase];
    PROCESS(R0);
    PROCESS(R1);
    PROCESS(R2);
    PROCESS(R3);
    R0 = Na; R1 = Nb; R2 = Nc; R3 = Nd;
  }
  int r = deg - i;  // 0..3 remaining, already resident in R0..R2
  if (r > 0) PROCESS(R0);
  if (r > 1) PROCESS(R1);
  if (r > 2) PROCESS(R2);
#undef PROCESS

  float inv = (deg > 0) ? 1.f / s : 0.f;  // deg==0 -> out = bias
#pragma unroll
  for (int j = 0; j < 8; j++)
    out[n * F + dimBase + j] = acc[j] * inv + bias[dimBase + j];
}

// ---------------------------------------------------------------------------
extern "C" void kernel_launch(void* const* d_in, const int* in_sizes, int n_in,
                              void* d_out, int out_size, void* d_ws,
                              size_t ws_size, hipStream_t stream) {
  const float* feat = (const float*)d_in[0];
  const int* src = (const int*)d_in[1];
  const int* dst = (const int*)d_in[2];
  const float* W = (const float*)d_in[3];
  const float* bias = (const float*)d_in[4];
  float* out = (float*)d_out;

  const int N = in_sizes[0] / F;
  const int E = in_sizes[1];

  // workspace layout
  char* ws = (char*)d_ws;
  ushort_t* ftb = (ushort_t*)ws;                 // N*128 bf16 = 12.8 MB
  size_t ftB = (size_t)N * F * sizeof(ushort_t);
  ftB = (ftB + 255) & ~(size_t)255;
  int* counts = (int*)(ws + ftB);                // N
  int* offs = counts + N;                        // N
  int* bsums = offs + N;                         // 256
  int* csr = bsums + 256;                        // E

  hipMemsetAsync(counts, 0, (size_t)N * sizeof(int), stream);

  gemm_ft_kernel<<<(N + 63) / 64, 256, 0, stream>>>(feat, W, ftb, N);
  hist_kernel<<<(E + 255) / 256, 256, 0, stream>>>(dst, counts, E);

  int nb = (N + 255) / 256;  // 196 for N=50000 (must be <= 256)
  scan_block_kernel<<<nb, 256, 0, stream>>>(counts, offs, bsums, N);
  scan_finish_kernel<<<nb, 256, 0, stream>>>(offs, bsums, N);

  scatter8_kernel<<<SCAT_BLOCKS, 256, 0, stream>>>(src, dst, offs, csr, E);

  aggregate_kernel<<<(N * 16 + 255) / 256, 256, 0, stream>>>(
      ftb, offs, counts, csr, bias, out, N);
}

// Round 4
// 126.183 us; speedup vs baseline: 1.5842x; 1.2135x over previous
//
#include <hip/hip_runtime.h>
#include <math.h>

#define F 128
#define HEADS 4
#define DHEAD 32
#define HIST_BLOCKS 1024

typedef unsigned short ushort_t;

// round-to-nearest-even fp32 -> bf16
__device__ __forceinline__ ushort_t f2bf(float x) {
  unsigned u = __float_as_uint(x);
  unsigned r = u + 0x7FFFu + ((u >> 16) & 1u);
  return (ushort_t)(r >> 16);
}

// unpack 8 packed bf16 (as int4) -> 8 fp32
__device__ __forceinline__ void unpack8(const int4& r, float* v) {
  int rr[4] = {r.x, r.y, r.z, r.w};
#pragma unroll
  for (int q = 0; q < 4; q++) {
    unsigned u = (unsigned)rr[q];
    v[2 * q] = __uint_as_float(u << 16);
    v[2 * q + 1] = __uint_as_float(u & 0xFFFF0000u);
  }
}

// class of a node: cls = n / 6250 via magic multiply (exact for n < 2.9e6)
#define CLS_MAGIC 687195u
__device__ __forceinline__ int node_cls(int n) {
  return (int)__umulhi((unsigned)n, CLS_MAGIC);
}

// ---------------------------------------------------------------------------
// K0: zero counts (replaces runtime fillBuffer kernel which ran at 0.44 GB/s)
// ---------------------------------------------------------------------------
__global__ __launch_bounds__(256) void zero_counts_kernel(int* __restrict__ p,
                                                          int N) {
  int i4 = blockIdx.x * 256 + threadIdx.x;
  int base = i4 * 4;
  if (base + 3 < N) {
    *(int4*)&p[base] = make_int4(0, 0, 0, 0);
  } else if (base < N) {
    for (int j = base; j < N; j++) p[j] = 0;
  }
}

// ---------------------------------------------------------------------------
// K1: fused  [blocks 0..gemmBlocks)  : ft = feat @ W  (fp32 VALU, bf16 out)
//            [gemmBlocks..+HIST_BLOCKS): histogram of dst -> counts
// The two are data-independent; fusing hides hist behind the GEMM.
// ---------------------------------------------------------------------------
__global__ __launch_bounds__(256) void gemm_hist_kernel(
    const float* __restrict__ A, const float* __restrict__ W,
    ushort_t* __restrict__ ftb, int N, const int* __restrict__ dst,
    int* __restrict__ counts, int E, int gemmBlocks) {
  if ((int)blockIdx.x >= gemmBlocks) {
    // ---- histogram path (no __syncthreads on this path) ----
    int hb = blockIdx.x - gemmBlocks;
    for (int i = hb * 256 + (int)threadIdx.x; i < E; i += HIST_BLOCKS * 256)
      atomicAdd(&counts[dst[i]], 1);
    return;
  }
  // ---- GEMM path ----
  __shared__ float sA[64][36];
  __shared__ float sB[32][128];
  const int t = threadIdx.x;
  const int tx = t & 15;   // 16 col-groups of 8 cols
  const int ty = t >> 4;   // 16 row-groups of 4 rows
  const int row0 = blockIdx.x * 64;

  float acc[4][8];
#pragma unroll
  for (int r = 0; r < 4; r++)
#pragma unroll
    for (int c = 0; c < 8; c++) acc[r][c] = 0.f;

  for (int k0 = 0; k0 < F; k0 += 32) {
    __syncthreads();
#pragma unroll
    for (int rep = 0; rep < 2; rep++) {
      int idx = t + rep * 256;
      int r = idx >> 3, c4 = idx & 7;
      int gr = row0 + r;
      float4 v = make_float4(0.f, 0.f, 0.f, 0.f);
      if (gr < N) v = *(const float4*)&A[gr * F + k0 + c4 * 4];
      *(float4*)&sA[r][c4 * 4] = v;
    }
#pragma unroll
    for (int rep = 0; rep < 4; rep++) {
      int idx = t + rep * 256;
      int r = idx >> 5, c4 = idx & 31;
      *(float4*)&sB[r][c4 * 4] = *(const float4*)&W[(k0 + r) * F + c4 * 4];
    }
    __syncthreads();
#pragma unroll
    for (int kk = 0; kk < 32; kk += 4) {
      float4 a4[4];
#pragma unroll
      for (int r = 0; r < 4; r++) a4[r] = *(const float4*)&sA[ty * 4 + r][kk];
#pragma unroll
      for (int j = 0; j < 4; j++) {
        float bv[8];
        *(float4*)&bv[0] = *(const float4*)&sB[kk + j][tx * 8];
        *(float4*)&bv[4] = *(const float4*)&sB[kk + j][tx * 8 + 4];
#pragma unroll
        for (int r = 0; r < 4; r++) {
          float av = (&a4[r].x)[j];
#pragma unroll
          for (int c = 0; c < 8; c++) acc[r][c] = fmaf(av, bv[c], acc[r][c]);
        }
      }
    }
  }
#pragma unroll
  for (int r = 0; r < 4; r++) {
    int gr = row0 + ty * 4 + r;
    if (gr < N) {
      union { ushort_t us[8]; int4 v; } pk;
#pragma unroll
      for (int c = 0; c < 8; c++) pk.us[c] = f2bf(acc[r][c]);
      *(int4*)&ftb[gr * F + tx * 8] = pk.v;
    }
  }
}

// ---------------------------------------------------------------------------
// K3: scan. block-local exclusive + block sums, then per-block bsum prefix add
// ---------------------------------------------------------------------------
__global__ void scan_block_kernel(const int* __restrict__ counts,
                                  int* __restrict__ offs,
                                  int* __restrict__ bsums, int N) {
  __shared__ int s[256];
  int t = threadIdx.x, i = blockIdx.x * 256 + t;
  int v = (i < N) ? counts[i] : 0;
  s[t] = v;
  __syncthreads();
  for (int d = 1; d < 256; d <<= 1) {
    int x = (t >= d) ? s[t - d] : 0;
    __syncthreads();
    s[t] += x;
    __syncthreads();
  }
  if (i < N) offs[i] = s[t] - v;  // block-local exclusive
  if (t == 255) bsums[blockIdx.x] = s[255];
}

__global__ void scan_finish_kernel(int* __restrict__ offs,
                                   const int* __restrict__ bsums, int N) {
  int t = threadIdx.x, b = blockIdx.x;
  int v = (t < b) ? bsums[t] : 0;  // nb <= 256 guaranteed
#pragma unroll
  for (int d = 32; d > 0; d >>= 1) v += __shfl_down(v, d, 64);
  __shared__ int wsum[4];
  if ((t & 63) == 0) wsum[t >> 6] = v;
  __syncthreads();
  int total = wsum[0] + wsum[1] + wsum[2] + wsum[3];
  int i = b * 256 + t;
  if (i < N) offs[i] += total;
}

// ---------------------------------------------------------------------------
// K4: XCD-class-filtered scatter. Block class x = bid&7 commits only edges
// with dst in node-range x (6250 nodes); csr/offs lines for a range are then
// written by ONE XCD -> stores merge in its L2 before writeback.
// After this kernel offs[n] == end of node n's range; start = end - counts[n].
// ---------------------------------------------------------------------------
#define SCAT_BLOCKS 2048
__global__ __launch_bounds__(256) void scatter8_kernel(
    const int* __restrict__ src, const int* __restrict__ dst,
    int* __restrict__ offs, int* __restrict__ csr, int E) {
  const int cls = blockIdx.x & 7;
  const int bx = blockIdx.x >> 3;          // class-local block index
  const int nbc = SCAT_BLOCKS / 8;         // blocks per class
  const int seg = (E + nbc - 1) / nbc;     // edges per class-block
  const int e0 = bx * seg;
  const int e1 = min(e0 + seg, E);
  for (int e = e0 + (int)threadIdx.x; e < e1; e += 256) {
    int d = dst[e];
    if (node_cls(d) == cls) {
      int pos = atomicAdd(&offs[d], 1);
      csr[pos] = src[e];
    }
  }
}

// ---------------------------------------------------------------------------
// K5: fused per-node online-softmax aggregation, bf16 ft, 4-deep pipelined.
// 4 lanes per (node, head), 8 dims/lane; a node's 16 lanes read each edge's
// 256 B bf16 row fully coalesced.
// ---------------------------------------------------------------------------
__global__ __launch_bounds__(256) void aggregate_kernel(
    const ushort_t* __restrict__ ftb, const int* __restrict__ offs_end,
    const int* __restrict__ counts, const int* __restrict__ csr,
    const float* __restrict__ bias, float* __restrict__ out, int N) {
  const int T = blockIdx.x * 256 + threadIdx.x;
  if (T >= N * 16) return;
  const int sub = T & 3;  // quarter of a head's D
  const int p = T >> 2;   // (node, head)
  const int h = p & 3;
  const int n = p >> 2;
  const int dimBase = h * DHEAD + sub * 8;

  const int deg = counts[n];
  const int off = offs_end[n] - deg;

  float ftd[8];
  {
    int4 r = *(const int4*)&ftb[n * F + dimBase];
    unpack8(r, ftd);
  }

  const float LOG2E = 1.4426950408889634f;
  float m = -INFINITY, s = 0.f;
  float acc[8];
#pragma unroll
  for (int j = 0; j < 8; j++) acc[j] = 0.f;

#define PROCESS(RX)                                              \
  do {                                                           \
    float v[8];                                                  \
    unpack8(RX, v);                                              \
    float part = 0.f;                                            \
    _Pragma("unroll") for (int j = 0; j < 8; j++) part =         \
        fmaf(ftd[j], v[j], part);                                \
    part += __shfl_xor(part, 1, 4);                              \
    part += __shfl_xor(part, 2, 4);                              \
    float el = part * LOG2E;                                     \
    float mn = fmaxf(m, el);                                     \
    float scale = exp2f(m - mn);                                 \
    float w = exp2f(el - mn);                                    \
    s = fmaf(s, scale, w);                                       \
    _Pragma("unroll") for (int j = 0; j < 8; j++) acc[j] =       \
        fmaf(acc[j], scale, w * v[j]);                           \
    m = mn;                                                      \
  } while (0)

  int4 R0 = make_int4(0, 0, 0, 0), R1 = R0, R2 = R0, R3 = R0;
  if (deg > 0) {
    int dm1 = deg - 1;
    int s0 = csr[off];
    int s1 = csr[off + min(1, dm1)];
    int s2 = csr[off + min(2, dm1)];
    int s3 = csr[off + min(3, dm1)];
    R0 = *(const int4*)&ftb[s0 * F + dimBase];
    R1 = *(const int4*)&ftb[s1 * F + dimBase];
    R2 = *(const int4*)&ftb[s2 * F + dimBase];
    R3 = *(const int4*)&ftb[s3 * F + dimBase];
  }
  int i = 0;
  for (; i + 4 <= deg; i += 4) {
    // branchless 4-ahead prefetch (clamped; duplicate loads are cache hits)
    int dm1 = deg - 1;
    int sa = csr[off + min(i + 4, dm1)];
    int sb = csr[off + min(i + 5, dm1)];
    int sc = csr[off + min(i + 6, dm1)];
    int sd = csr[off + min(i + 7, dm1)];
    int4 Na = *(const int4*)&ftb[sa * F + dimBase];
    int4 Nb = *(const int4*)&ftb[sb * F + dimBase];
    int4 Nc = *(const int4*)&ftb[sc * F + dimBase];
    int4 Nd = *(const int4*)&ftb[sd * F + dimBase];
    PROCESS(R0);
    PROCESS(R1);
    PROCESS(R2);
    PROCESS(R3);
    R0 = Na; R1 = Nb; R2 = Nc; R3 = Nd;
  }
  int r = deg - i;  // 0..3 remaining, already resident in R0..R2
  if (r > 0) PROCESS(R0);
  if (r > 1) PROCESS(R1);
  if (r > 2) PROCESS(R2);
#undef PROCESS

  float inv = (deg > 0) ? 1.f / s : 0.f;  // deg==0 -> out = bias
#pragma unroll
  for (int j = 0; j < 8; j++)
    out[n * F + dimBase + j] = acc[j] * inv + bias[dimBase + j];
}

// ---------------------------------------------------------------------------
extern "C" void kernel_launch(void* const* d_in, const int* in_sizes, int n_in,
                              void* d_out, int out_size, void* d_ws,
                              size_t ws_size, hipStream_t stream) {
  const float* feat = (const float*)d_in[0];
  const int* src = (const int*)d_in[1];
  const int* dst = (const int*)d_in[2];
  const float* W = (const float*)d_in[3];
  const float* bias = (const float*)d_in[4];
  float* out = (float*)d_out;

  const int N = in_sizes[0] / F;
  const int E = in_sizes[1];

  // workspace layout
  char* ws = (char*)d_ws;
  ushort_t* ftb = (ushort_t*)ws;                 // N*128 bf16 = 12.8 MB
  size_t ftB = (size_t)N * F * sizeof(ushort_t);
  ftB = (ftB + 255) & ~(size_t)255;
  int* counts = (int*)(ws + ftB);                // N
  int* offs = counts + N;                        // N
  int* bsums = offs + N;                         // 256
  int* csr = bsums + 256;                        // E

  zero_counts_kernel<<<(N + 1023) / 1024, 256, 0, stream>>>(counts, N);

  int gemmBlocks = (N + 63) / 64;
  gemm_hist_kernel<<<gemmBlocks + HIST_BLOCKS, 256, 0, stream>>>(
      feat, W, ftb, N, dst, counts, E, gemmBlocks);

  int nb = (N + 255) / 256;  // 196 for N=50000 (must be <= 256)
  scan_block_kernel<<<nb, 256, 0, stream>>>(counts, offs, bsums, N);
  scan_finish_kernel<<<nb, 256, 0, stream>>>(offs, bsums, N);

  scatter8_kernel<<<SCAT_BLOCKS, 256, 0, stream>>>(src, dst, offs, csr, E);

  aggregate_kernel<<<(N * 16 + 255) / 256, 256, 0, stream>>>(
      ftb, offs, counts, csr, bias, out, N);
}